// Round 17
// baseline (248.794 us; speedup 1.0000x reference)
//
#include <hip/hip_runtime.h>

// ECNR forward, R17 = R16 with L3 FUSED into the L2 epilogue:
//  After L2's kc-loop each lane holds 16 channel-values of one point (fp32).
//  Compute partial = sum_16 w3[ch]*sin(acc_r) in-register (w3 channels are
//  wave-uniform -> scalar loads), write 1 float to red, reduce 8/point at end.
//  Deletes: L2 H-writes, barriers B4+B6 (6 -> 4), the whole L3 LDS/MFMA
//  phase, and the bf16-lo L3 handoff (L3 now fp32 -> absmax improves).
//  w3 stored as fp32 (w3f) again; omega pre-scaling (R16) retained.

typedef unsigned int u32;
typedef unsigned short u16;
typedef __bf16 v8bf  __attribute__((ext_vector_type(8)));
typedef __bf16 v2bf  __attribute__((ext_vector_type(2)));
typedef float  v16f  __attribute__((ext_vector_type(16)));
typedef float  v2f   __attribute__((ext_vector_type(2)));
typedef u32    v4u   __attribute__((ext_vector_type(4)));
typedef u32    v2u   __attribute__((ext_vector_type(2)));

#define MFMA(a, b, c) __builtin_amdgcn_mfma_f32_32x32x16_bf16(a, b, c, 0, 0, 0)

#define HSTRIDE 136                 // u16; 272 B rows: 16B-aligned, bank-balanced
#define OMEGA_S 4.774648292756860f  // 30/(2*pi)

__device__ __forceinline__ float sinrev(float rev) {
    return __builtin_amdgcn_sinf(__builtin_amdgcn_fractf(rev));
}

__device__ __forceinline__ u32 pack2(float c) {
    __bf16 b0 = (__bf16)c;
    float  f0 = (float)b0;
    __bf16 b1 = (__bf16)(c - f0);
    return (u32)__builtin_bit_cast(u16, b0) |
           ((u32)__builtin_bit_cast(u16, b1) << 16);
}

// two floats -> packed lo (bf16x2) and packed hi (residual bf16x2), RNE
__device__ __forceinline__ void pk2(float s0, float s1, u32& lo, u32& hi) {
    v2f s; s[0] = s0; s[1] = s1;
    v2bf l = __builtin_convertvector(s, v2bf);        // v_cvt_pk_bf16_f32
    u32 lov = __builtin_bit_cast(u32, l);
    v2f lf;
    lf[0] = __builtin_bit_cast(float, lov << 16);
    lf[1] = __builtin_bit_cast(float, lov & 0xffff0000u);
    v2f r = s - lf;
    v2bf h = __builtin_convertvector(r, v2bf);
    lo = lov;
    hi = __builtin_bit_cast(u32, h);
}

#define PLO(a, b) __builtin_amdgcn_perm((a), (b), 0x05040100u)
#define PHI(a, b) __builtin_amdgcn_perm((a), (b), 0x07060302u)

// ---------------------------------------------------------------------------
// K1: dequant. L0/L1/L2 centroids scaled by OMEGA_S; biases scaled -> biasc;
// w3 dequantized to fp32 (w3f).
// ---------------------------------------------------------------------------
__global__ __launch_bounds__(512)
void ecnr_dequant(const float* __restrict__ cent0, const int* __restrict__ lab0,
                  const float* __restrict__ cent1, const int* __restrict__ lab1,
                  const float* __restrict__ cent2, const int* __restrict__ lab2,
                  const float* __restrict__ cent3, const int* __restrict__ lab3,
                  const float* __restrict__ bias0, const float* __restrict__ bias1,
                  const float* __restrict__ bias2,
                  u16* __restrict__ wpl1, u16* __restrict__ wpl2,
                  u16* __restrict__ w0pl, float* __restrict__ w3f,
                  float* __restrict__ biasc)
{
    __shared__ u32 cpk[256];
    const int t = threadIdx.x;

    if (blockIdx.x < 512) {
        const int m = blockIdx.x >> 1, L = blockIdx.x & 1;
        if (t < 256) cpk[t] = pack2((L ? cent2 : cent1)[t] * OMEGA_S);
        __syncthreads();
        const int* lab = (L ? lab2 : lab1) + (size_t)m * 16384;
        u16* base = (L ? wpl2 : wpl1) + (size_t)m * 32768;
        #pragma unroll
        for (int i = 0; i < 4; ++i) {
            const int id = i * 512 + t;
            const int n = id & 127, c = id >> 7;
            u32 g[8];
            #pragma unroll
            for (int j = 0; j < 8; ++j) g[j] = cpk[lab[(8 * c + j) * 128 + n]];
            v4u lo, hi;
            #pragma unroll
            for (int r = 0; r < 4; ++r) {
                lo[r] = PLO(g[2 * r + 1], g[2 * r]);
                hi[r] = PHI(g[2 * r + 1], g[2 * r]);
            }
            *(v4u*)(base + c * 1024 + n * 8)         = lo;
            *(v4u*)(base + 16384 + c * 1024 + n * 8) = hi;
        }
    } else {
        const int m = blockIdx.x - 512;
        if (t < 256) cpk[t] = pack2(cent0[t] * OMEGA_S);
        __syncthreads();
        if (t < 256) {
            const int n = t & 127, c = t >> 7;
            const int* lab = lab0 + (size_t)m * 2048;
            u32 g[8];
            #pragma unroll
            for (int j = 0; j < 8; ++j) g[j] = cpk[lab[(8 * c + j) * 128 + n]];
            v4u lo, hi;
            #pragma unroll
            for (int r = 0; r < 4; ++r) {
                lo[r] = PLO(g[2 * r + 1], g[2 * r]);
                hi[r] = PHI(g[2 * r + 1], g[2 * r]);
            }
            u16* b0 = w0pl + (size_t)m * 4096;
            *(v4u*)(b0 + c * 1024 + n * 8)        = lo;
            *(v4u*)(b0 + 2048 + c * 1024 + n * 8) = hi;
        } else if (t < 384) {
            const int kk = t - 256;
            w3f[(size_t)m * 128 + kk] = cent3[lab3[(size_t)m * 128 + kk]];
        }
        // scaled biases: biasc[m][0..127]=b0*s, [128..255]=b1*s, [256..383]=b2*s
        if (t < 384) {
            const int li = t >> 7, kk = t & 127;
            const float* bsrc = (li == 0) ? bias0 : (li == 1) ? bias1 : bias2;
            biasc[(size_t)m * 384 + t] = bsrc[m * 128 + kk] * OMEGA_S;
        }
    }
}

// ---------------------------------------------------------------------------
// K2: fused forward. LDS: Hlo/Hhi 2x17408 + biasS 1024 + red 2048 = 37888 B
// -> 4 blocks/CU. 4 barriers.
// ---------------------------------------------------------------------------
__global__ __launch_bounds__(512, 8)
void ecnr_fwd(const float* __restrict__ x,
              const int*   __restrict__ mlp_idx,
              const int*   __restrict__ block_idx,
              const float* __restrict__ latent,
              const float* __restrict__ bias3,
              const u16* __restrict__ wpl1, const u16* __restrict__ wpl2,
              const u16* __restrict__ w0pl, const float* __restrict__ w3f,
              const float* __restrict__ biasc,
              float* __restrict__ out)
{
    __shared__ __attribute__((aligned(16))) u16   Hlo[64 * HSTRIDE];
    __shared__ __attribute__((aligned(16))) u16   Hhi[64 * HSTRIDE];
    __shared__ __attribute__((aligned(16))) float biasS[2 * 128];
    __shared__ __attribute__((aligned(16))) float red[2 * 256];  // [pt][grp=nt*2+q][ln]

    // XCD swizzle (bijective): xcd=g[2:0], tile=g[7:3], sample=g[12:8]<<3|xcd
    const int g    = blockIdx.x;
    const int b    = ((g >> 8) << 3) | (g & 7);    // sample 0..255
    const int p0   = ((g >> 3) & 31) * 64;         // tile * 64
    const int m    = mlp_idx[b];

    const int t  = threadIdx.x;
    const int l  = t & 63, w = t >> 6;
    const int q  = l >> 5, ln = l & 31;
    const int pt = w & 1, nt = w >> 1;      // 2 pt x 4 nt tiles of 32x32
    const int mrow = pt * 32 + ln;          // point row (B operand / H row)
    const int nn   = nt * 32 + ln;          // channel (A operand / W row)
    const int bidx = nt * 32 + 4 * q;       // bias frag base index

    const float* bc = biasc + (size_t)m * 384;
    if (t < 128) {
        biasS[t]       = bc[128 + t];
        biasS[128 + t] = bc[256 + t];
    }
    const float* xp = x + (size_t)(b * 2048 + p0 + mrow) * 3;
    const float xv0 = xp[0], xv1 = xp[1], xv2 = xp[2];
    const u16* w0p = w0pl + (size_t)m * 4096 + q * 1024 + nn * 8;
    const v4u w0lo = *(const v4u*)(w0p);
    const v4u w0hi = *(const v4u*)(w0p + 2048);
    float4 b0f[4];
    #pragma unroll
    for (int gg = 0; gg < 4; ++gg)
        b0f[gg] = *(const float4*)(bc + bidx + 8 * gg);
    const float* zp = latent + ((size_t)m * 8 + block_idx[b]) * 13;
    float zr[8];
    #pragma unroll
    for (int j = 0; j < 8; ++j) zr[j] = zp[q * 5 + j];
    // w3 values for this wave's 16 output channels (wave-uniform)
    float w3v[16];
    {
        const float* w3b = w3f + (size_t)m * 128;
        #pragma unroll
        for (int r = 0; r < 16; ++r)
            w3v[r] = w3b[nt * 32 + (r & 3) + 8 * (r >> 2) + 4 * q];
    }

    // epilogue write bases (4 consecutive n per group, 8 n between groups)
    u16* lop = Hlo + mrow * HSTRIDE + nt * 32 + 4 * q;
    u16* hip = Hhi + mrow * HSTRIDE + nt * 32 + 4 * q;

    // ---- layer 0: A = W0 (regs, scaled), B = input^T (regs), 3 products ----
    {
        float fin[8];
        if (q == 0) {
            fin[0] = xv0; fin[1] = xv1; fin[2] = xv2;
            #pragma unroll
            for (int j = 0; j < 5; ++j) fin[3 + j] = zr[j];
        } else {
            #pragma unroll
            for (int j = 0; j < 8; ++j) fin[j] = zr[j];
        }
        v4u il, ih;
        #pragma unroll
        for (int r = 0; r < 4; ++r) {
            u32 plo, phi;
            pk2(fin[2 * r], fin[2 * r + 1], plo, phi);
            il[r] = plo; ih[r] = phi;
        }
        const v8bf inlo = __builtin_bit_cast(v8bf, il);
        const v8bf inhi = __builtin_bit_cast(v8bf, ih);
        const v8bf wl = __builtin_bit_cast(v8bf, w0lo);
        const v8bf wh = __builtin_bit_cast(v8bf, w0hi);
        v16f acc;
        #pragma unroll
        for (int gg = 0; gg < 4; ++gg) {
            acc[4 * gg] = b0f[gg].x; acc[4 * gg + 1] = b0f[gg].y;
            acc[4 * gg + 2] = b0f[gg].z; acc[4 * gg + 3] = b0f[gg].w;
        }
        acc = MFMA(wl, inlo, acc);
        acc = MFMA(wl, inhi, acc);
        acc = MFMA(wh, inlo, acc);
        #pragma unroll
        for (int gg = 0; gg < 4; ++gg) {
            const float s0 = sinrev(acc[4 * gg + 0]);
            const float s1 = sinrev(acc[4 * gg + 1]);
            const float s2 = sinrev(acc[4 * gg + 2]);
            const float s3 = sinrev(acc[4 * gg + 3]);
            u32 l0, h0, l1, h1;
            pk2(s0, s1, l0, h0);
            pk2(s2, s3, l1, h1);
            v2u lov, hiv;
            lov[0] = l0; lov[1] = l1;
            hiv[0] = h0; hiv[1] = h1;
            *(v2u*)(lop + 8 * gg) = lov;
            *(v2u*)(hip + 8 * gg) = hiv;
        }
    }
    __syncthreads();  // B1: H(L0) + biasS visible

    // ---- layers 1,2: A = W (wlo panel resident), B = H^T (LDS) ----
    const u16* HLO = Hlo + mrow * HSTRIDE + q * 8;
    const u16* HHI = Hhi + mrow * HSTRIDE + q * 8;
    #pragma unroll 1
    for (int L = 0; L < 2; ++L) {
        const u16* Wb = (L ? wpl2 : wpl1) + (size_t)m * 32768 + q * 1024 + nn * 8;
        v16f acc;
        #pragma unroll
        for (int gg = 0; gg < 4; ++gg) {
            const float4 bv = *(const float4*)&biasS[L * 128 + bidx + 8 * gg];
            acc[4 * gg] = bv.x; acc[4 * gg + 1] = bv.y;
            acc[4 * gg + 2] = bv.z; acc[4 * gg + 3] = bv.w;
        }
        v4u wl8[8];
        #pragma unroll
        for (int kc = 0; kc < 8; ++kc)
            wl8[kc] = *(const v4u*)(Wb + kc * 2048);
        #pragma unroll
        for (int kc = 0; kc < 8; ++kc) {
            const v4u whv = *(const v4u*)(Wb + kc * 2048 + 16384);  // issue early
            const v8bf hlo = *(const v8bf*)(HLO + kc * 16);
            const v8bf hhi = *(const v8bf*)(HHI + kc * 16);
            acc = MFMA(__builtin_bit_cast(v8bf, wl8[kc]), hlo, acc);
            acc = MFMA(__builtin_bit_cast(v8bf, wl8[kc]), hhi, acc);
            acc = MFMA(__builtin_bit_cast(v8bf, whv), hlo, acc);
        }
        if (L == 0) {
            __syncthreads();  // B2: all H(L0) reads done
            #pragma unroll
            for (int gg = 0; gg < 4; ++gg) {
                const float s0 = sinrev(acc[4 * gg + 0]);
                const float s1 = sinrev(acc[4 * gg + 1]);
                const float s2 = sinrev(acc[4 * gg + 2]);
                const float s3 = sinrev(acc[4 * gg + 3]);
                u32 l0, h0, l1, h1;
                pk2(s0, s1, l0, h0);
                pk2(s2, s3, l1, h1);
                v2u lov, hiv;
                lov[0] = l0; lov[1] = l1;
                hiv[0] = h0; hiv[1] = h1;
                *(v2u*)(lop + 8 * gg) = lov;
                *(v2u*)(hip + 8 * gg) = hiv;
            }
            __syncthreads();  // B3: H(L1) visible
        } else {
            // ---- fused L3: partial = sum_16 w3[ch]*sin(acc_r), fp32 ----
            float s = 0.0f;
            #pragma unroll
            for (int r = 0; r < 16; ++r)
                s = __builtin_fmaf(w3v[r], sinrev(acc[r]), s);
            red[pt * 256 + (nt * 2 + q) * 32 + ln] = s;
        }
    }
    __syncthreads();  // B4: red visible

    if (t < 64) {
        const float* rp = red + (t >> 5) * 256 + (t & 31);
        float o = bias3[m];
        #pragma unroll
        for (int gg = 0; gg < 8; ++gg) o += rp[gg * 32];
        out[(size_t)b * 2048 + p0 + t] = o;
    }
}

extern "C" void kernel_launch(void* const* d_in, const int* in_sizes, int n_in,
                              void* d_out, int out_size, void* d_ws, size_t ws_size,
                              hipStream_t stream) {
    (void)in_sizes; (void)n_in; (void)out_size; (void)ws_size;
    u16*   wpl1  = (u16*)d_ws;                          // 16 MB
    u16*   wpl2  = wpl1 + (size_t)256 * 32768;          // 16 MB
    u16*   w0pl  = wpl2 + (size_t)256 * 32768;          // 2 MB
    float* w3f   = (float*)(w0pl + (size_t)256 * 4096); // 128 KB
    float* biasc = w3f + (size_t)256 * 128;             // 384 KB

    ecnr_dequant<<<768, 512, 0, stream>>>(
        (const float*)d_in[4],  (const int*)d_in[5],
        (const float*)d_in[7],  (const int*)d_in[8],
        (const float*)d_in[10], (const int*)d_in[11],
        (const float*)d_in[13], (const int*)d_in[14],
        (const float*)d_in[6],  (const float*)d_in[9], (const float*)d_in[12],
        wpl1, wpl2, w0pl, w3f, biasc);

    ecnr_fwd<<<8192, 512, 0, stream>>>(
        (const float*)d_in[0], (const int*)d_in[1], (const int*)d_in[2],
        (const float*)d_in[3],
        (const float*)d_in[15],
        wpl1, wpl2, w0pl, w3f, biasc,
        (float*)d_out);
}

// Round 18
// 237.219 us; speedup vs baseline: 1.0488x; 1.0488x over previous
//
#include <hip/hip_runtime.h>

// ECNR forward, R18 = R17 with the spill fixed: w3 fragments are loaded
// INSIDE the L==1 branch AFTER the kc-loop (wl8 regs dead there), as 4
// float4 loads. R17 loaded w3v[16] at kernel top -> 16 extra live VGPRs
// across the kc-loop -> scratch spills (WRITE_SIZE 2->30 MB, fwd 139->156).
//  Structure: L3 fused into L2 epilogue (4 barriers), omega pre-scaling,
//  wlo panel resident, pk-cvt epilogues. absmax ~0.033.

typedef unsigned int u32;
typedef unsigned short u16;
typedef __bf16 v8bf  __attribute__((ext_vector_type(8)));
typedef __bf16 v2bf  __attribute__((ext_vector_type(2)));
typedef float  v16f  __attribute__((ext_vector_type(16)));
typedef float  v2f   __attribute__((ext_vector_type(2)));
typedef u32    v4u   __attribute__((ext_vector_type(4)));
typedef u32    v2u   __attribute__((ext_vector_type(2)));

#define MFMA(a, b, c) __builtin_amdgcn_mfma_f32_32x32x16_bf16(a, b, c, 0, 0, 0)

#define HSTRIDE 136                 // u16; 272 B rows: 16B-aligned, bank-balanced
#define OMEGA_S 4.774648292756860f  // 30/(2*pi)

__device__ __forceinline__ float sinrev(float rev) {
    return __builtin_amdgcn_sinf(__builtin_amdgcn_fractf(rev));
}

__device__ __forceinline__ u32 pack2(float c) {
    __bf16 b0 = (__bf16)c;
    float  f0 = (float)b0;
    __bf16 b1 = (__bf16)(c - f0);
    return (u32)__builtin_bit_cast(u16, b0) |
           ((u32)__builtin_bit_cast(u16, b1) << 16);
}

// two floats -> packed lo (bf16x2) and packed hi (residual bf16x2), RNE
__device__ __forceinline__ void pk2(float s0, float s1, u32& lo, u32& hi) {
    v2f s; s[0] = s0; s[1] = s1;
    v2bf l = __builtin_convertvector(s, v2bf);        // v_cvt_pk_bf16_f32
    u32 lov = __builtin_bit_cast(u32, l);
    v2f lf;
    lf[0] = __builtin_bit_cast(float, lov << 16);
    lf[1] = __builtin_bit_cast(float, lov & 0xffff0000u);
    v2f r = s - lf;
    v2bf h = __builtin_convertvector(r, v2bf);
    lo = lov;
    hi = __builtin_bit_cast(u32, h);
}

#define PLO(a, b) __builtin_amdgcn_perm((a), (b), 0x05040100u)
#define PHI(a, b) __builtin_amdgcn_perm((a), (b), 0x07060302u)

// ---------------------------------------------------------------------------
// K1: dequant (unchanged from R17). L0/L1/L2 scaled by OMEGA_S; w3 fp32.
// ---------------------------------------------------------------------------
__global__ __launch_bounds__(512)
void ecnr_dequant(const float* __restrict__ cent0, const int* __restrict__ lab0,
                  const float* __restrict__ cent1, const int* __restrict__ lab1,
                  const float* __restrict__ cent2, const int* __restrict__ lab2,
                  const float* __restrict__ cent3, const int* __restrict__ lab3,
                  const float* __restrict__ bias0, const float* __restrict__ bias1,
                  const float* __restrict__ bias2,
                  u16* __restrict__ wpl1, u16* __restrict__ wpl2,
                  u16* __restrict__ w0pl, float* __restrict__ w3f,
                  float* __restrict__ biasc)
{
    __shared__ u32 cpk[256];
    const int t = threadIdx.x;

    if (blockIdx.x < 512) {
        const int m = blockIdx.x >> 1, L = blockIdx.x & 1;
        if (t < 256) cpk[t] = pack2((L ? cent2 : cent1)[t] * OMEGA_S);
        __syncthreads();
        const int* lab = (L ? lab2 : lab1) + (size_t)m * 16384;
        u16* base = (L ? wpl2 : wpl1) + (size_t)m * 32768;
        #pragma unroll
        for (int i = 0; i < 4; ++i) {
            const int id = i * 512 + t;
            const int n = id & 127, c = id >> 7;
            u32 g[8];
            #pragma unroll
            for (int j = 0; j < 8; ++j) g[j] = cpk[lab[(8 * c + j) * 128 + n]];
            v4u lo, hi;
            #pragma unroll
            for (int r = 0; r < 4; ++r) {
                lo[r] = PLO(g[2 * r + 1], g[2 * r]);
                hi[r] = PHI(g[2 * r + 1], g[2 * r]);
            }
            *(v4u*)(base + c * 1024 + n * 8)         = lo;
            *(v4u*)(base + 16384 + c * 1024 + n * 8) = hi;
        }
    } else {
        const int m = blockIdx.x - 512;
        if (t < 256) cpk[t] = pack2(cent0[t] * OMEGA_S);
        __syncthreads();
        if (t < 256) {
            const int n = t & 127, c = t >> 7;
            const int* lab = lab0 + (size_t)m * 2048;
            u32 g[8];
            #pragma unroll
            for (int j = 0; j < 8; ++j) g[j] = cpk[lab[(8 * c + j) * 128 + n]];
            v4u lo, hi;
            #pragma unroll
            for (int r = 0; r < 4; ++r) {
                lo[r] = PLO(g[2 * r + 1], g[2 * r]);
                hi[r] = PHI(g[2 * r + 1], g[2 * r]);
            }
            u16* b0 = w0pl + (size_t)m * 4096;
            *(v4u*)(b0 + c * 1024 + n * 8)        = lo;
            *(v4u*)(b0 + 2048 + c * 1024 + n * 8) = hi;
        } else if (t < 384) {
            const int kk = t - 256;
            w3f[(size_t)m * 128 + kk] = cent3[lab3[(size_t)m * 128 + kk]];
        }
        if (t < 384) {
            const int li = t >> 7, kk = t & 127;
            const float* bsrc = (li == 0) ? bias0 : (li == 1) ? bias1 : bias2;
            biasc[(size_t)m * 384 + t] = bsrc[m * 128 + kk] * OMEGA_S;
        }
    }
}

// ---------------------------------------------------------------------------
// K2: fused forward. LDS: Hlo/Hhi 2x17408 + biasS 1024 + red 2048 = 37888 B
// -> 4 blocks/CU. 4 barriers.
// ---------------------------------------------------------------------------
__global__ __launch_bounds__(512, 8)
void ecnr_fwd(const float* __restrict__ x,
              const int*   __restrict__ mlp_idx,
              const int*   __restrict__ block_idx,
              const float* __restrict__ latent,
              const float* __restrict__ bias3,
              const u16* __restrict__ wpl1, const u16* __restrict__ wpl2,
              const u16* __restrict__ w0pl, const float* __restrict__ w3f,
              const float* __restrict__ biasc,
              float* __restrict__ out)
{
    __shared__ __attribute__((aligned(16))) u16   Hlo[64 * HSTRIDE];
    __shared__ __attribute__((aligned(16))) u16   Hhi[64 * HSTRIDE];
    __shared__ __attribute__((aligned(16))) float biasS[2 * 128];
    __shared__ __attribute__((aligned(16))) float red[2 * 256];  // [pt][grp=nt*2+q][ln]

    // XCD swizzle (bijective): xcd=g[2:0], tile=g[7:3], sample=g[12:8]<<3|xcd
    const int g    = blockIdx.x;
    const int b    = ((g >> 8) << 3) | (g & 7);    // sample 0..255
    const int p0   = ((g >> 3) & 31) * 64;         // tile * 64
    const int m    = mlp_idx[b];

    const int t  = threadIdx.x;
    const int l  = t & 63, w = t >> 6;
    const int q  = l >> 5, ln = l & 31;
    const int pt = w & 1, nt = w >> 1;      // 2 pt x 4 nt tiles of 32x32
    const int mrow = pt * 32 + ln;          // point row (B operand / H row)
    const int nn   = nt * 32 + ln;          // channel (A operand / W row)
    const int bidx = nt * 32 + 4 * q;       // bias frag base index

    const float* bc = biasc + (size_t)m * 384;
    if (t < 128) {
        biasS[t]       = bc[128 + t];
        biasS[128 + t] = bc[256 + t];
    }
    const float* xp = x + (size_t)(b * 2048 + p0 + mrow) * 3;
    const float xv0 = xp[0], xv1 = xp[1], xv2 = xp[2];
    const u16* w0p = w0pl + (size_t)m * 4096 + q * 1024 + nn * 8;
    const v4u w0lo = *(const v4u*)(w0p);
    const v4u w0hi = *(const v4u*)(w0p + 2048);
    float4 b0f[4];
    #pragma unroll
    for (int gg = 0; gg < 4; ++gg)
        b0f[gg] = *(const float4*)(bc + bidx + 8 * gg);
    const float* zp = latent + ((size_t)m * 8 + block_idx[b]) * 13;
    float zr[8];
    #pragma unroll
    for (int j = 0; j < 8; ++j) zr[j] = zp[q * 5 + j];

    // epilogue write bases (4 consecutive n per group, 8 n between groups)
    u16* lop = Hlo + mrow * HSTRIDE + nt * 32 + 4 * q;
    u16* hip = Hhi + mrow * HSTRIDE + nt * 32 + 4 * q;

    // ---- layer 0: A = W0 (regs, scaled), B = input^T (regs), 3 products ----
    {
        float fin[8];
        if (q == 0) {
            fin[0] = xv0; fin[1] = xv1; fin[2] = xv2;
            #pragma unroll
            for (int j = 0; j < 5; ++j) fin[3 + j] = zr[j];
        } else {
            #pragma unroll
            for (int j = 0; j < 8; ++j) fin[j] = zr[j];
        }
        v4u il, ih;
        #pragma unroll
        for (int r = 0; r < 4; ++r) {
            u32 plo, phi;
            pk2(fin[2 * r], fin[2 * r + 1], plo, phi);
            il[r] = plo; ih[r] = phi;
        }
        const v8bf inlo = __builtin_bit_cast(v8bf, il);
        const v8bf inhi = __builtin_bit_cast(v8bf, ih);
        const v8bf wl = __builtin_bit_cast(v8bf, w0lo);
        const v8bf wh = __builtin_bit_cast(v8bf, w0hi);
        v16f acc;
        #pragma unroll
        for (int gg = 0; gg < 4; ++gg) {
            acc[4 * gg] = b0f[gg].x; acc[4 * gg + 1] = b0f[gg].y;
            acc[4 * gg + 2] = b0f[gg].z; acc[4 * gg + 3] = b0f[gg].w;
        }
        acc = MFMA(wl, inlo, acc);
        acc = MFMA(wl, inhi, acc);
        acc = MFMA(wh, inlo, acc);
        #pragma unroll
        for (int gg = 0; gg < 4; ++gg) {
            const float s0 = sinrev(acc[4 * gg + 0]);
            const float s1 = sinrev(acc[4 * gg + 1]);
            const float s2 = sinrev(acc[4 * gg + 2]);
            const float s3 = sinrev(acc[4 * gg + 3]);
            u32 l0, h0, l1, h1;
            pk2(s0, s1, l0, h0);
            pk2(s2, s3, l1, h1);
            v2u lov, hiv;
            lov[0] = l0; lov[1] = l1;
            hiv[0] = h0; hiv[1] = h1;
            *(v2u*)(lop + 8 * gg) = lov;
            *(v2u*)(hip + 8 * gg) = hiv;
        }
    }
    __syncthreads();  // B1: H(L0) + biasS visible

    // ---- layers 1,2: A = W (wlo panel resident), B = H^T (LDS) ----
    const u16* HLO = Hlo + mrow * HSTRIDE + q * 8;
    const u16* HHI = Hhi + mrow * HSTRIDE + q * 8;
    #pragma unroll 1
    for (int L = 0; L < 2; ++L) {
        const u16* Wb = (L ? wpl2 : wpl1) + (size_t)m * 32768 + q * 1024 + nn * 8;
        v16f acc;
        #pragma unroll
        for (int gg = 0; gg < 4; ++gg) {
            const float4 bv = *(const float4*)&biasS[L * 128 + bidx + 8 * gg];
            acc[4 * gg] = bv.x; acc[4 * gg + 1] = bv.y;
            acc[4 * gg + 2] = bv.z; acc[4 * gg + 3] = bv.w;
        }
        v4u wl8[8];
        #pragma unroll
        for (int kc = 0; kc < 8; ++kc)
            wl8[kc] = *(const v4u*)(Wb + kc * 2048);
        #pragma unroll
        for (int kc = 0; kc < 8; ++kc) {
            const v4u whv = *(const v4u*)(Wb + kc * 2048 + 16384);  // issue early
            const v8bf hlo = *(const v8bf*)(HLO + kc * 16);
            const v8bf hhi = *(const v8bf*)(HHI + kc * 16);
            acc = MFMA(__builtin_bit_cast(v8bf, wl8[kc]), hlo, acc);
            acc = MFMA(__builtin_bit_cast(v8bf, wl8[kc]), hhi, acc);
            acc = MFMA(__builtin_bit_cast(v8bf, whv), hlo, acc);
        }
        if (L == 0) {
            __syncthreads();  // B2: all H(L0) reads done
            #pragma unroll
            for (int gg = 0; gg < 4; ++gg) {
                const float s0 = sinrev(acc[4 * gg + 0]);
                const float s1 = sinrev(acc[4 * gg + 1]);
                const float s2 = sinrev(acc[4 * gg + 2]);
                const float s3 = sinrev(acc[4 * gg + 3]);
                u32 l0, h0, l1, h1;
                pk2(s0, s1, l0, h0);
                pk2(s2, s3, l1, h1);
                v2u lov, hiv;
                lov[0] = l0; lov[1] = l1;
                hiv[0] = h0; hiv[1] = h1;
                *(v2u*)(lop + 8 * gg) = lov;
                *(v2u*)(hip + 8 * gg) = hiv;
            }
            __syncthreads();  // B3: H(L1) visible
        } else {
            // ---- fused L3: load w3 frags NOW (wl8 dead; no spill) ----
            const float* w3b = w3f + (size_t)m * 128 + nt * 32 + 4 * q;
            float4 w3g[4];
            #pragma unroll
            for (int gg = 0; gg < 4; ++gg)
                w3g[gg] = *(const float4*)(w3b + 8 * gg);
            float s = 0.0f;
            #pragma unroll
            for (int gg = 0; gg < 4; ++gg) {
                s = __builtin_fmaf(w3g[gg].x, sinrev(acc[4 * gg + 0]), s);
                s = __builtin_fmaf(w3g[gg].y, sinrev(acc[4 * gg + 1]), s);
                s = __builtin_fmaf(w3g[gg].z, sinrev(acc[4 * gg + 2]), s);
                s = __builtin_fmaf(w3g[gg].w, sinrev(acc[4 * gg + 3]), s);
            }
            red[pt * 256 + (nt * 2 + q) * 32 + ln] = s;
        }
    }
    __syncthreads();  // B4: red visible

    if (t < 64) {
        const float* rp = red + (t >> 5) * 256 + (t & 31);
        float o = bias3[m];
        #pragma unroll
        for (int gg = 0; gg < 8; ++gg) o += rp[gg * 32];
        out[(size_t)b * 2048 + p0 + t] = o;
    }
}

extern "C" void kernel_launch(void* const* d_in, const int* in_sizes, int n_in,
                              void* d_out, int out_size, void* d_ws, size_t ws_size,
                              hipStream_t stream) {
    (void)in_sizes; (void)n_in; (void)out_size; (void)ws_size;
    u16*   wpl1  = (u16*)d_ws;                          // 16 MB
    u16*   wpl2  = wpl1 + (size_t)256 * 32768;          // 16 MB
    u16*   w0pl  = wpl2 + (size_t)256 * 32768;          // 2 MB
    float* w3f   = (float*)(w0pl + (size_t)256 * 4096); // 128 KB
    float* biasc = w3f + (size_t)256 * 128;             // 384 KB

    ecnr_dequant<<<768, 512, 0, stream>>>(
        (const float*)d_in[4],  (const int*)d_in[5],
        (const float*)d_in[7],  (const int*)d_in[8],
        (const float*)d_in[10], (const int*)d_in[11],
        (const float*)d_in[13], (const int*)d_in[14],
        (const float*)d_in[6],  (const float*)d_in[9], (const float*)d_in[12],
        wpl1, wpl2, w0pl, w3f, biasc);

    ecnr_fwd<<<8192, 512, 0, stream>>>(
        (const float*)d_in[0], (const int*)d_in[1], (const int*)d_in[2],
        (const float*)d_in[3],
        (const float*)d_in[15],
        wpl1, wpl2, w0pl, w3f, biasc,
        (float*)d_out);
}